// Round 5
// baseline (1076.512 us; speedup 1.0000x reference)
//
#include <hip/hip_runtime.h>
#include <hip/hip_bf16.h>

#define IN_DIM 784
#define HIDDEN 1024
#define OUT_DIM 10
#define BATCH 256

// layer-1 split-K tiling
#define C_I 49        // i-chunk size (784 = 16 * 49)
#define N_CH 16       // number of i-chunks
#define H_T 32        // h-tile per block

// layer-2 split-K
#define KSPLIT 4
#define KCHUNK (HIDDEN / KSPLIT)   // 256

typedef float __attribute__((ext_vector_type(4))) f32x4;

// ---------------------------------------------------------------------------
// K1: tiled transpose x [256][784] -> xT [784][256], coalesced on both sides.
// ---------------------------------------------------------------------------
__global__ __launch_bounds__(256) void k_transpose_x(
    const float* __restrict__ x, float* __restrict__ xT)
{
    __shared__ float tile[32][33];
    const int tx = threadIdx.x & 31;
    const int ty = threadIdx.x >> 5;       // 0..7
    const int i0 = blockIdx.x * 32;        // 25 blocks, last half-valid
    const int b0 = blockIdx.y * 32;

    #pragma unroll
    for (int r = 0; r < 4; r++) {
        const int bb = ty + r * 8;
        const int i  = i0 + tx;
        tile[bb][tx] = (i < IN_DIM) ? x[(b0 + bb) * IN_DIM + i] : 0.f;
    }
    __syncthreads();
    #pragma unroll
    for (int r = 0; r < 4; r++) {
        const int ii = ty + r * 8;
        if (i0 + ii < IN_DIM)
            xT[(i0 + ii) * BATCH + b0 + tx] = tile[tx][ii];
    }
}

// ---------------------------------------------------------------------------
// K2: DropConnect layer 1, split-K over i.
// ROUND-5 A/B: mask loads are PLAIN cached loads (was nontemporal).
// m13's 6.29 TB/s ceiling was measured with cached loads; nt-bit streaming
// rate is unverified and is the prime suspect for the ~70 µs BW shortfall.
// Everything else unchanged to isolate the variable.
// ---------------------------------------------------------------------------
__global__ __launch_bounds__(1024, 8) void k_layer1_split(
    const float* __restrict__ W1, const float* __restrict__ mask,
    const float* __restrict__ xT, float* __restrict__ partial)
{
    const int ht   = blockIdx.x;     // 0..31
    const int c    = blockIdx.y;     // 0..15
    const int h0   = ht * H_T;
    const int i0   = c * C_I;
    const int t    = threadIdx.x;
    const int bg   = t & 63;         // batch group: b = 4*bg..4*bg+3
    const int slot = t >> 6;         // 0..15 -> h = h0 + 2*slot + {0,1}

    __shared__ f32x4 xs[C_I][64];        // 50176 B
    __shared__ float wsh[H_T][C_I];      // 6272 B

    {
        const f32x4* src = (const f32x4*)(xT + i0 * BATCH);
        f32x4* dst = &xs[0][0];
        for (int idx = t; idx < C_I * 64; idx += 1024)
            dst[idx] = src[idx];
    }
    {
        float* dst = &wsh[0][0];
        for (int idx = t; idx < H_T * C_I; idx += 1024) {
            const int hh = idx / C_I, ii = idx - hh * C_I;
            dst[idx] = W1[(h0 + hh) * IN_DIM + i0 + ii];
        }
    }
    __syncthreads();

    const int hh0 = slot * 2;
    const f32x4* mrow0 =
        (const f32x4*)(mask + ((size_t)(h0 + hh0) * IN_DIM + i0) * BATCH) + bg;
    const f32x4* mrow1 = mrow0 + (size_t)IN_DIM * 64;

    f32x4 a0 = {0.f, 0.f, 0.f, 0.f};
    f32x4 a1 = {0.f, 0.f, 0.f, 0.f};
    #pragma unroll 2
    for (int i = 0; i < C_I; i++) {
        const f32x4 m0 = mrow0[i * 64];          // plain cached load
        const f32x4 m1 = mrow1[i * 64];          // plain cached load
        const f32x4 xv = xs[i][bg];
        const float w0 = wsh[hh0][i];
        const float w1 = wsh[hh0 + 1][i];
        a0.x = fmaf(w0, m0.x * xv.x, a0.x);
        a0.y = fmaf(w0, m0.y * xv.y, a0.y);
        a0.z = fmaf(w0, m0.z * xv.z, a0.z);
        a0.w = fmaf(w0, m0.w * xv.w, a0.w);
        a1.x = fmaf(w1, m1.x * xv.x, a1.x);
        a1.y = fmaf(w1, m1.y * xv.y, a1.y);
        a1.z = fmaf(w1, m1.z * xv.z, a1.z);
        a1.w = fmaf(w1, m1.w * xv.w, a1.w);
    }

    f32x4* p4 = (f32x4*)partial + ((size_t)c * HIDDEN + h0 + hh0) * 64 + bg;
    p4[0]  = a0;
    p4[64] = a1;
}

// ---------------------------------------------------------------------------
// K3: reduce 16 partials -> h1T[h][b] = relu(b1[h] + sum_c partial)
// ---------------------------------------------------------------------------
__global__ __launch_bounds__(256) void k_reduce_h1(
    const float* __restrict__ partial, const float* __restrict__ b1,
    float* __restrict__ h1T)
{
    const int t  = threadIdx.x;
    const int bg = t & 63;
    const int h  = blockIdx.x * 4 + (t >> 6);

    const f32x4* p4 = (const f32x4*)partial;
    f32x4 s = {0.f, 0.f, 0.f, 0.f};
    #pragma unroll
    for (int cc = 0; cc < N_CH; cc++) {
        const f32x4 v = p4[((size_t)cc * HIDDEN + h) * 64 + bg];
        s.x += v.x; s.y += v.y; s.z += v.z; s.w += v.w;
    }
    const float b = b1[h];
    f32x4 r;
    r.x = fmaxf(s.x + b, 0.f);
    r.y = fmaxf(s.y + b, 0.f);
    r.z = fmaxf(s.z + b, 0.f);
    r.w = fmaxf(s.w + b, 0.f);
    ((f32x4*)h1T)[h * 64 + bg] = r;
}

// ---------------------------------------------------------------------------
// K4: layer 2 GEMM, split-K x4 (4 blocks/CU, 8 barrier-separated sub-tiles).
// ---------------------------------------------------------------------------
__global__ __launch_bounds__(256) void k_layer2_split(
    const float* __restrict__ h1T, const float* __restrict__ W2,
    float* __restrict__ h2p)
{
    const int t  = threadIdx.x;
    const int jj = t & 31;
    const int bg = t >> 5;
    const int b0 = blockIdx.x * 32;
    const int j0 = blockIdx.y * 32;
    const int hbase = blockIdx.z * KCHUNK;

    __shared__ __align__(16) float Ash[32][32];
    __shared__ float Bsh[32][33];

    float acc0 = 0.f, acc1 = 0.f, acc2 = 0.f, acc3 = 0.f;

    for (int s = 0; s < KCHUNK; s += 32) {
        const int h0 = hbase + s;
        #pragma unroll
        for (int r = 0; r < 4; r++) {
            const int idx = t + r * 256;
            const int hh = idx >> 5, bb = idx & 31;
            Ash[hh][bb] = h1T[(h0 + hh) * BATCH + b0 + bb];
        }
        #pragma unroll
        for (int r = 0; r < 4; r++) {
            const int idx = t + r * 256;
            const int jl = idx >> 5, hl = idx & 31;
            Bsh[hl][jl] = W2[(j0 + jl) * HIDDEN + h0 + hl];
        }
        __syncthreads();
        #pragma unroll 8
        for (int hh = 0; hh < 32; hh++) {
            const float w = Bsh[hh][jj];
            const float4 a = *(const float4*)&Ash[hh][bg * 4];
            acc0 = fmaf(a.x, w, acc0);
            acc1 = fmaf(a.y, w, acc1);
            acc2 = fmaf(a.z, w, acc2);
            acc3 = fmaf(a.w, w, acc3);
        }
        __syncthreads();
    }

    float* dst = h2p + (size_t)blockIdx.z * (BATCH * HIDDEN);
    const int base = (b0 + bg * 4) * HIDDEN + j0 + jj;
    dst[base + 0 * HIDDEN] = acc0;
    dst[base + 1 * HIDDEN] = acc1;
    dst[base + 2 * HIDDEN] = acc2;
    dst[base + 3 * HIDDEN] = acc3;
}

// ---------------------------------------------------------------------------
// K5: layer 3, fused with layer-2 k-split reduction + bias + relu.
// ---------------------------------------------------------------------------
__global__ __launch_bounds__(256) void k_layer3(
    const float* __restrict__ h2p, const float* __restrict__ W3,
    const float* __restrict__ b2, const float* __restrict__ b3,
    float* __restrict__ out)
{
    const int b = blockIdx.x;
    const int t = threadIdx.x;
    const int lane = t & 63, wid = t >> 6;

    __shared__ float hbuf[HIDDEN];
    #pragma unroll
    for (int r = 0; r < 4; r++) {
        const int h = t + r * 256;
        float v = b2[h];
        #pragma unroll
        for (int kc = 0; kc < KSPLIT; kc++)
            v += h2p[(size_t)kc * (BATCH * HIDDEN) + b * HIDDEN + h];
        hbuf[h] = fmaxf(v, 0.f);
    }
    __syncthreads();

    float acc[OUT_DIM];
    #pragma unroll
    for (int o = 0; o < OUT_DIM; o++) acc[o] = 0.f;

    for (int h = t; h < HIDDEN; h += 256) {
        const float v = hbuf[h];
        #pragma unroll
        for (int o = 0; o < OUT_DIM; o++)
            acc[o] = fmaf(v, W3[o * HIDDEN + h], acc[o]);
    }

    __shared__ float red[4][OUT_DIM];
    #pragma unroll
    for (int o = 0; o < OUT_DIM; o++) {
        float v = acc[o];
        for (int off = 32; off > 0; off >>= 1)
            v += __shfl_down(v, off);
        if (lane == 0) red[wid][o] = v;
    }
    __syncthreads();
    if (t < OUT_DIM) {
        out[b * OUT_DIM + t] =
            red[0][t] + red[1][t] + red[2][t] + red[3][t] + b3[t];
    }
}

extern "C" void kernel_launch(void* const* d_in, const int* in_sizes, int n_in,
                              void* d_out, int out_size, void* d_ws, size_t ws_size,
                              hipStream_t stream) {
    const float* x    = (const float*)d_in[0];
    const float* mask = (const float*)d_in[1];
    const float* W1   = (const float*)d_in[2];
    const float* b1   = (const float*)d_in[3];
    const float* W2   = (const float*)d_in[4];
    const float* b2   = (const float*)d_in[5];
    const float* W3   = (const float*)d_in[6];
    const float* b3   = (const float*)d_in[7];
    float* out = (float*)d_out;

    float* ws      = (float*)d_ws;
    float* xT      = ws;                               // 784*256
    float* h1T     = xT + IN_DIM * BATCH;              // 1024*256
    float* h2p     = h1T + HIDDEN * BATCH;             // 4*256*1024 (4 MB)
    float* partial = h2p + KSPLIT * BATCH * HIDDEN;    // 16*1024*256 (16 MB)

    k_transpose_x<<<dim3(25, BATCH / 32), 256, 0, stream>>>(x, xT);
    k_layer1_split<<<dim3(HIDDEN / H_T, N_CH), 1024, 0, stream>>>(W1, mask, xT, partial);
    k_reduce_h1<<<HIDDEN / 4, 256, 0, stream>>>(partial, b1, h1T);
    k_layer2_split<<<dim3(BATCH / 32, HIDDEN / 32, KSPLIT), 256, 0, stream>>>(h1T, W2, h2p);
    k_layer3<<<BATCH, 256, 0, stream>>>(h2p, W3, b2, b3, out);
}

// Round 6
// 1046.966 us; speedup vs baseline: 1.0282x; 1.0282x over previous
//
#include <hip/hip_runtime.h>
#include <hip/hip_bf16.h>

#define IN_DIM 784
#define HIDDEN 1024
#define OUT_DIM 10
#define BATCH 256

// layer-1 split-K tiling
#define C_I 49        // i-chunk size (784 = 16 * 49)
#define N_CH 16       // number of i-chunks
#define H_T 16        // h-tile per block (one h-row per slot)

// layer-2 split-K
#define KSPLIT 4
#define KCHUNK (HIDDEN / KSPLIT)   // 256

typedef float __attribute__((ext_vector_type(4))) f32x4;

// ---------------------------------------------------------------------------
// K1: tiled transpose x [256][784] -> xT [784][256], coalesced on both sides.
// ---------------------------------------------------------------------------
__global__ __launch_bounds__(256) void k_transpose_x(
    const float* __restrict__ x, float* __restrict__ xT)
{
    __shared__ float tile[32][33];
    const int tx = threadIdx.x & 31;
    const int ty = threadIdx.x >> 5;       // 0..7
    const int i0 = blockIdx.x * 32;        // 25 blocks, last half-valid
    const int b0 = blockIdx.y * 32;

    #pragma unroll
    for (int r = 0; r < 4; r++) {
        const int bb = ty + r * 8;
        const int i  = i0 + tx;
        tile[bb][tx] = (i < IN_DIM) ? x[(b0 + bb) * IN_DIM + i] : 0.f;
    }
    __syncthreads();
    #pragma unroll
    for (int r = 0; r < 4; r++) {
        const int ii = ty + r * 8;
        if (i0 + ii < IN_DIM)
            xT[(i0 + ii) * BATCH + b0 + tx] = tile[tx][ii];
    }
}

// ---------------------------------------------------------------------------
// K2: DropConnect layer 1, split-K over i.
// nt loads RESTORED (round-5 A/B: cached mask loads cost +40 us — the
// read-once 822 MB stream thrashes L2/L3; nt streams faster).
// ROUND-6 variable: ONE h-row per slot (was 2 interleaved). Each wave now
// advances a single contiguous 50 KB stream with up to 7 nt loads in
// flight (unroll 7; 49 = 7*7) instead of 2 interleaved streams at depth 4.
// Halves device-wide concurrent streams, doubles per-stream prefetch depth.
// ---------------------------------------------------------------------------
__global__ __launch_bounds__(1024, 8) void k_layer1_split(
    const float* __restrict__ W1, const float* __restrict__ mask,
    const float* __restrict__ xT, float* __restrict__ partial)
{
    const int ht   = blockIdx.x;     // 0..63
    const int c    = blockIdx.y;     // 0..15
    const int h0   = ht * H_T;
    const int i0   = c * C_I;
    const int t    = threadIdx.x;
    const int bg   = t & 63;         // batch group: b = 4*bg..4*bg+3
    const int slot = t >> 6;         // 0..15 -> h = h0 + slot

    __shared__ f32x4 xs[C_I][64];        // 50176 B
    __shared__ float wsh[H_T][C_I];      // 3136 B

    {
        const f32x4* src = (const f32x4*)(xT + i0 * BATCH);
        f32x4* dst = &xs[0][0];
        for (int idx = t; idx < C_I * 64; idx += 1024)
            dst[idx] = src[idx];
    }
    {
        float* dst = &wsh[0][0];
        for (int idx = t; idx < H_T * C_I; idx += 1024) {
            const int hh = idx / C_I, ii = idx - hh * C_I;
            dst[idx] = W1[(h0 + hh) * IN_DIM + i0 + ii];
        }
    }
    __syncthreads();

    const int h = h0 + slot;
    const f32x4* mrow =
        (const f32x4*)(mask + ((size_t)h * IN_DIM + i0) * BATCH) + bg;

    f32x4 a = {0.f, 0.f, 0.f, 0.f};
    #pragma unroll 7
    for (int i = 0; i < C_I; i++) {
        const f32x4 m  = __builtin_nontemporal_load(mrow + i * 64);
        const f32x4 xv = xs[i][bg];
        const float w  = wsh[slot][i];
        a.x = fmaf(w, m.x * xv.x, a.x);
        a.y = fmaf(w, m.y * xv.y, a.y);
        a.z = fmaf(w, m.z * xv.z, a.z);
        a.w = fmaf(w, m.w * xv.w, a.w);
    }

    // partial[c][h][b]: cached stores (L2/L3-resident for the reduce)
    f32x4* p4 = (f32x4*)partial + ((size_t)c * HIDDEN + h) * 64 + bg;
    *p4 = a;
}

// ---------------------------------------------------------------------------
// K3: reduce 16 partials -> h1T[h][b] = relu(b1[h] + sum_c partial)
// ---------------------------------------------------------------------------
__global__ __launch_bounds__(256) void k_reduce_h1(
    const float* __restrict__ partial, const float* __restrict__ b1,
    float* __restrict__ h1T)
{
    const int t  = threadIdx.x;
    const int bg = t & 63;
    const int h  = blockIdx.x * 4 + (t >> 6);

    const f32x4* p4 = (const f32x4*)partial;
    f32x4 s = {0.f, 0.f, 0.f, 0.f};
    #pragma unroll
    for (int cc = 0; cc < N_CH; cc++) {
        const f32x4 v = p4[((size_t)cc * HIDDEN + h) * 64 + bg];
        s.x += v.x; s.y += v.y; s.z += v.z; s.w += v.w;
    }
    const float b = b1[h];
    f32x4 r;
    r.x = fmaxf(s.x + b, 0.f);
    r.y = fmaxf(s.y + b, 0.f);
    r.z = fmaxf(s.z + b, 0.f);
    r.w = fmaxf(s.w + b, 0.f);
    ((f32x4*)h1T)[h * 64 + bg] = r;
}

// ---------------------------------------------------------------------------
// K4: layer 2 GEMM, split-K x4 (4 blocks/CU, 8 barrier-separated sub-tiles).
// ---------------------------------------------------------------------------
__global__ __launch_bounds__(256) void k_layer2_split(
    const float* __restrict__ h1T, const float* __restrict__ W2,
    float* __restrict__ h2p)
{
    const int t  = threadIdx.x;
    const int jj = t & 31;
    const int bg = t >> 5;
    const int b0 = blockIdx.x * 32;
    const int j0 = blockIdx.y * 32;
    const int hbase = blockIdx.z * KCHUNK;

    __shared__ __align__(16) float Ash[32][32];
    __shared__ float Bsh[32][33];

    float acc0 = 0.f, acc1 = 0.f, acc2 = 0.f, acc3 = 0.f;

    for (int s = 0; s < KCHUNK; s += 32) {
        const int h0 = hbase + s;
        #pragma unroll
        for (int r = 0; r < 4; r++) {
            const int idx = t + r * 256;
            const int hh = idx >> 5, bb = idx & 31;
            Ash[hh][bb] = h1T[(h0 + hh) * BATCH + b0 + bb];
        }
        #pragma unroll
        for (int r = 0; r < 4; r++) {
            const int idx = t + r * 256;
            const int jl = idx >> 5, hl = idx & 31;
            Bsh[hl][jl] = W2[(j0 + jl) * HIDDEN + h0 + hl];
        }
        __syncthreads();
        #pragma unroll 8
        for (int hh = 0; hh < 32; hh++) {
            const float w = Bsh[hh][jj];
            const float4 a = *(const float4*)&Ash[hh][bg * 4];
            acc0 = fmaf(a.x, w, acc0);
            acc1 = fmaf(a.y, w, acc1);
            acc2 = fmaf(a.z, w, acc2);
            acc3 = fmaf(a.w, w, acc3);
        }
        __syncthreads();
    }

    float* dst = h2p + (size_t)blockIdx.z * (BATCH * HIDDEN);
    const int base = (b0 + bg * 4) * HIDDEN + j0 + jj;
    dst[base + 0 * HIDDEN] = acc0;
    dst[base + 1 * HIDDEN] = acc1;
    dst[base + 2 * HIDDEN] = acc2;
    dst[base + 3 * HIDDEN] = acc3;
}

// ---------------------------------------------------------------------------
// K5: layer 3, fused with layer-2 k-split reduction + bias + relu.
// ---------------------------------------------------------------------------
__global__ __launch_bounds__(256) void k_layer3(
    const float* __restrict__ h2p, const float* __restrict__ W3,
    const float* __restrict__ b2, const float* __restrict__ b3,
    float* __restrict__ out)
{
    const int b = blockIdx.x;
    const int t = threadIdx.x;
    const int lane = t & 63, wid = t >> 6;

    __shared__ float hbuf[HIDDEN];
    #pragma unroll
    for (int r = 0; r < 4; r++) {
        const int h = t + r * 256;
        float v = b2[h];
        #pragma unroll
        for (int kc = 0; kc < KSPLIT; kc++)
            v += h2p[(size_t)kc * (BATCH * HIDDEN) + b * HIDDEN + h];
        hbuf[h] = fmaxf(v, 0.f);
    }
    __syncthreads();

    float acc[OUT_DIM];
    #pragma unroll
    for (int o = 0; o < OUT_DIM; o++) acc[o] = 0.f;

    for (int h = t; h < HIDDEN; h += 256) {
        const float v = hbuf[h];
        #pragma unroll
        for (int o = 0; o < OUT_DIM; o++)
            acc[o] = fmaf(v, W3[o * HIDDEN + h], acc[o]);
    }

    __shared__ float red[4][OUT_DIM];
    #pragma unroll
    for (int o = 0; o < OUT_DIM; o++) {
        float v = acc[o];
        for (int off = 32; off > 0; off >>= 1)
            v += __shfl_down(v, off);
        if (lane == 0) red[wid][o] = v;
    }
    __syncthreads();
    if (t < OUT_DIM) {
        out[b * OUT_DIM + t] =
            red[0][t] + red[1][t] + red[2][t] + red[3][t] + b3[t];
    }
}

extern "C" void kernel_launch(void* const* d_in, const int* in_sizes, int n_in,
                              void* d_out, int out_size, void* d_ws, size_t ws_size,
                              hipStream_t stream) {
    const float* x    = (const float*)d_in[0];
    const float* mask = (const float*)d_in[1];
    const float* W1   = (const float*)d_in[2];
    const float* b1   = (const float*)d_in[3];
    const float* W2   = (const float*)d_in[4];
    const float* b2   = (const float*)d_in[5];
    const float* W3   = (const float*)d_in[6];
    const float* b3   = (const float*)d_in[7];
    float* out = (float*)d_out;

    float* ws      = (float*)d_ws;
    float* xT      = ws;                               // 784*256
    float* h1T     = xT + IN_DIM * BATCH;              // 1024*256
    float* h2p     = h1T + HIDDEN * BATCH;             // 4*256*1024 (4 MB)
    float* partial = h2p + KSPLIT * BATCH * HIDDEN;    // 16*1024*256 (16 MB)

    k_transpose_x<<<dim3(25, BATCH / 32), 256, 0, stream>>>(x, xT);
    k_layer1_split<<<dim3(HIDDEN / H_T, N_CH), 1024, 0, stream>>>(W1, mask, xT, partial);
    k_reduce_h1<<<HIDDEN / 4, 256, 0, stream>>>(partial, b1, h1T);
    k_layer2_split<<<dim3(BATCH / 32, HIDDEN / 32, KSPLIT), 256, 0, stream>>>(h1T, W2, h2p);
    k_layer3<<<BATCH, 256, 0, stream>>>(h2p, W3, b2, b3, out);
}

// Round 7
// 1037.482 us; speedup vs baseline: 1.0376x; 1.0091x over previous
//
#include <hip/hip_runtime.h>
#include <hip/hip_bf16.h>

#define IN_DIM 784
#define HIDDEN 1024
#define OUT_DIM 10
#define BATCH 256

// layer-1 split-K tiling
#define C_I 49        // i-chunk size (784 = 16 * 49)
#define N_CH 16       // number of i-chunks
#define H_T 32        // h-tile per block (round-4 best: 2 rows per wave-slot)

// layer-2 split-K
#define KSPLIT 4
#define KCHUNK (HIDDEN / KSPLIT)   // 256

typedef float __attribute__((ext_vector_type(4))) f32x4;

// ---------------------------------------------------------------------------
// K1: tiled transpose x [256][784] -> xT [784][256], coalesced on both sides.
// ---------------------------------------------------------------------------
__global__ __launch_bounds__(256) void k_transpose_x(
    const float* __restrict__ x, float* __restrict__ xT)
{
    __shared__ float tile[32][33];
    const int tx = threadIdx.x & 31;
    const int ty = threadIdx.x >> 5;       // 0..7
    const int i0 = blockIdx.x * 32;        // 25 blocks, last half-valid
    const int b0 = blockIdx.y * 32;

    #pragma unroll
    for (int r = 0; r < 4; r++) {
        const int bb = ty + r * 8;
        const int i  = i0 + tx;
        tile[bb][tx] = (i < IN_DIM) ? x[(b0 + bb) * IN_DIM + i] : 0.f;
    }
    __syncthreads();
    #pragma unroll
    for (int r = 0; r < 4; r++) {
        const int ii = ty + r * 8;
        if (i0 + ii < IN_DIM)
            xT[(i0 + ii) * BATCH + b0 + tx] = tile[tx][ii];
    }
}

// ---------------------------------------------------------------------------
// K2: DropConnect layer 1, split-K over i. ROUND-4 BEST CONFIG (H_T=32,
// two interleaved h-rows per wave-slot, nt mask loads) with ONE change:
// #pragma unroll 7 on the i-loop -> 14 nt loads in flight per wave
// (was 4 with unroll 2). A/B history: cached loads +40us (L2/L3 thrash);
// single-stream/unroll-7 restructure neutral; this isolates MLP depth.
// ---------------------------------------------------------------------------
__global__ __launch_bounds__(1024, 8) void k_layer1_split(
    const float* __restrict__ W1, const float* __restrict__ mask,
    const float* __restrict__ xT, float* __restrict__ partial)
{
    const int ht   = blockIdx.x;     // 0..31
    const int c    = blockIdx.y;     // 0..15
    const int h0   = ht * H_T;
    const int i0   = c * C_I;
    const int t    = threadIdx.x;
    const int bg   = t & 63;         // batch group: b = 4*bg..4*bg+3
    const int slot = t >> 6;         // 0..15 -> h = h0 + 2*slot + {0,1}

    __shared__ f32x4 xs[C_I][64];        // 50176 B
    __shared__ float wsh[H_T][C_I];      // 6272 B

    {
        const f32x4* src = (const f32x4*)(xT + i0 * BATCH);
        f32x4* dst = &xs[0][0];
        for (int idx = t; idx < C_I * 64; idx += 1024)
            dst[idx] = src[idx];
    }
    {
        float* dst = &wsh[0][0];
        for (int idx = t; idx < H_T * C_I; idx += 1024) {
            const int hh = idx / C_I, ii = idx - hh * C_I;
            dst[idx] = W1[(h0 + hh) * IN_DIM + i0 + ii];
        }
    }
    __syncthreads();

    const int hh0 = slot * 2;
    const f32x4* mrow0 =
        (const f32x4*)(mask + ((size_t)(h0 + hh0) * IN_DIM + i0) * BATCH) + bg;
    const f32x4* mrow1 = mrow0 + (size_t)IN_DIM * 64;

    f32x4 a0 = {0.f, 0.f, 0.f, 0.f};
    f32x4 a1 = {0.f, 0.f, 0.f, 0.f};
    #pragma unroll 7
    for (int i = 0; i < C_I; i++) {
        const f32x4 m0 = __builtin_nontemporal_load(mrow0 + i * 64);
        const f32x4 m1 = __builtin_nontemporal_load(mrow1 + i * 64);
        const f32x4 xv = xs[i][bg];
        const float w0 = wsh[hh0][i];
        const float w1 = wsh[hh0 + 1][i];
        a0.x = fmaf(w0, m0.x * xv.x, a0.x);
        a0.y = fmaf(w0, m0.y * xv.y, a0.y);
        a0.z = fmaf(w0, m0.z * xv.z, a0.z);
        a0.w = fmaf(w0, m0.w * xv.w, a0.w);
        a1.x = fmaf(w1, m1.x * xv.x, a1.x);
        a1.y = fmaf(w1, m1.y * xv.y, a1.y);
        a1.z = fmaf(w1, m1.z * xv.z, a1.z);
        a1.w = fmaf(w1, m1.w * xv.w, a1.w);
    }

    f32x4* p4 = (f32x4*)partial + ((size_t)c * HIDDEN + h0 + hh0) * 64 + bg;
    p4[0]  = a0;
    p4[64] = a1;
}

// ---------------------------------------------------------------------------
// K3: reduce 16 partials -> h1T[h][b] = relu(b1[h] + sum_c partial)
// ---------------------------------------------------------------------------
__global__ __launch_bounds__(256) void k_reduce_h1(
    const float* __restrict__ partial, const float* __restrict__ b1,
    float* __restrict__ h1T)
{
    const int t  = threadIdx.x;
    const int bg = t & 63;
    const int h  = blockIdx.x * 4 + (t >> 6);

    const f32x4* p4 = (const f32x4*)partial;
    f32x4 s = {0.f, 0.f, 0.f, 0.f};
    #pragma unroll
    for (int cc = 0; cc < N_CH; cc++) {
        const f32x4 v = p4[((size_t)cc * HIDDEN + h) * 64 + bg];
        s.x += v.x; s.y += v.y; s.z += v.z; s.w += v.w;
    }
    const float b = b1[h];
    f32x4 r;
    r.x = fmaxf(s.x + b, 0.f);
    r.y = fmaxf(s.y + b, 0.f);
    r.z = fmaxf(s.z + b, 0.f);
    r.w = fmaxf(s.w + b, 0.f);
    ((f32x4*)h1T)[h * 64 + bg] = r;
}

// ---------------------------------------------------------------------------
// K4: layer 2 GEMM, split-K x4 (4 blocks/CU, 8 barrier-separated sub-tiles).
// ---------------------------------------------------------------------------
__global__ __launch_bounds__(256) void k_layer2_split(
    const float* __restrict__ h1T, const float* __restrict__ W2,
    float* __restrict__ h2p)
{
    const int t  = threadIdx.x;
    const int jj = t & 31;
    const int bg = t >> 5;
    const int b0 = blockIdx.x * 32;
    const int j0 = blockIdx.y * 32;
    const int hbase = blockIdx.z * KCHUNK;

    __shared__ __align__(16) float Ash[32][32];
    __shared__ float Bsh[32][33];

    float acc0 = 0.f, acc1 = 0.f, acc2 = 0.f, acc3 = 0.f;

    for (int s = 0; s < KCHUNK; s += 32) {
        const int h0 = hbase + s;
        #pragma unroll
        for (int r = 0; r < 4; r++) {
            const int idx = t + r * 256;
            const int hh = idx >> 5, bb = idx & 31;
            Ash[hh][bb] = h1T[(h0 + hh) * BATCH + b0 + bb];
        }
        #pragma unroll
        for (int r = 0; r < 4; r++) {
            const int idx = t + r * 256;
            const int jl = idx >> 5, hl = idx & 31;
            Bsh[hl][jl] = W2[(j0 + jl) * HIDDEN + h0 + hl];
        }
        __syncthreads();
        #pragma unroll 8
        for (int hh = 0; hh < 32; hh++) {
            const float w = Bsh[hh][jj];
            const float4 a = *(const float4*)&Ash[hh][bg * 4];
            acc0 = fmaf(a.x, w, acc0);
            acc1 = fmaf(a.y, w, acc1);
            acc2 = fmaf(a.z, w, acc2);
            acc3 = fmaf(a.w, w, acc3);
        }
        __syncthreads();
    }

    float* dst = h2p + (size_t)blockIdx.z * (BATCH * HIDDEN);
    const int base = (b0 + bg * 4) * HIDDEN + j0 + jj;
    dst[base + 0 * HIDDEN] = acc0;
    dst[base + 1 * HIDDEN] = acc1;
    dst[base + 2 * HIDDEN] = acc2;
    dst[base + 3 * HIDDEN] = acc3;
}

// ---------------------------------------------------------------------------
// K5: layer 3, fused with layer-2 k-split reduction + bias + relu.
// ---------------------------------------------------------------------------
__global__ __launch_bounds__(256) void k_layer3(
    const float* __restrict__ h2p, const float* __restrict__ W3,
    const float* __restrict__ b2, const float* __restrict__ b3,
    float* __restrict__ out)
{
    const int b = blockIdx.x;
    const int t = threadIdx.x;
    const int lane = t & 63, wid = t >> 6;

    __shared__ float hbuf[HIDDEN];
    #pragma unroll
    for (int r = 0; r < 4; r++) {
        const int h = t + r * 256;
        float v = b2[h];
        #pragma unroll
        for (int kc = 0; kc < KSPLIT; kc++)
            v += h2p[(size_t)kc * (BATCH * HIDDEN) + b * HIDDEN + h];
        hbuf[h] = fmaxf(v, 0.f);
    }
    __syncthreads();

    float acc[OUT_DIM];
    #pragma unroll
    for (int o = 0; o < OUT_DIM; o++) acc[o] = 0.f;

    for (int h = t; h < HIDDEN; h += 256) {
        const float v = hbuf[h];
        #pragma unroll
        for (int o = 0; o < OUT_DIM; o++)
            acc[o] = fmaf(v, W3[o * HIDDEN + h], acc[o]);
    }

    __shared__ float red[4][OUT_DIM];
    #pragma unroll
    for (int o = 0; o < OUT_DIM; o++) {
        float v = acc[o];
        for (int off = 32; off > 0; off >>= 1)
            v += __shfl_down(v, off);
        if (lane == 0) red[wid][o] = v;
    }
    __syncthreads();
    if (t < OUT_DIM) {
        out[b * OUT_DIM + t] =
            red[0][t] + red[1][t] + red[2][t] + red[3][t] + b3[t];
    }
}

extern "C" void kernel_launch(void* const* d_in, const int* in_sizes, int n_in,
                              void* d_out, int out_size, void* d_ws, size_t ws_size,
                              hipStream_t stream) {
    const float* x    = (const float*)d_in[0];
    const float* mask = (const float*)d_in[1];
    const float* W1   = (const float*)d_in[2];
    const float* b1   = (const float*)d_in[3];
    const float* W2   = (const float*)d_in[4];
    const float* b2   = (const float*)d_in[5];
    const float* W3   = (const float*)d_in[6];
    const float* b3   = (const float*)d_in[7];
    float* out = (float*)d_out;

    float* ws      = (float*)d_ws;
    float* xT      = ws;                               // 784*256
    float* h1T     = xT + IN_DIM * BATCH;              // 1024*256
    float* h2p     = h1T + HIDDEN * BATCH;             // 4*256*1024 (4 MB)
    float* partial = h2p + KSPLIT * BATCH * HIDDEN;    // 16*1024*256 (16 MB)

    k_transpose_x<<<dim3(25, BATCH / 32), 256, 0, stream>>>(x, xT);
    k_layer1_split<<<dim3(HIDDEN / H_T, N_CH), 1024, 0, stream>>>(W1, mask, xT, partial);
    k_reduce_h1<<<HIDDEN / 4, 256, 0, stream>>>(partial, b1, h1T);
    k_layer2_split<<<dim3(BATCH / 32, HIDDEN / 32, KSPLIT), 256, 0, stream>>>(h1T, W2, h2p);
    k_layer3<<<BATCH, 256, 0, stream>>>(h2p, W3, b2, b3, out);
}